// Round 1
// baseline (2689.378 us; speedup 1.0000x reference)
//
#include <hip/hip_runtime.h>

// Problem: x(64,512) int -> emb(1024); h_i = W_op(h_{i-1}+e_i)+b (W_op = stored W as
// row-major right-multiplier on row vectors); pred_mean = mean_i(Wc h_i + bc); CE loss.
// Restructured: r_m = Wc*W^m (10x1024). Sum_i Wc h_i = Sum_j Acc_{512-j} . e_j
//   + (512*Wc + Sum_{M=1..511} Acc_M) . b,  Acc_M = Sum_{m<=M} r_m.
// r_m built via: P=W^16 (4 squarings); chain s_a = s_{a-1}P (a=1..31); sweep
// R[t] = R[t-1]*W (t=0..15) on stacked 320x1024 block; m = 16a+t+1.
//
// ws layout (floats), total 16,328,704 floats = 65.3 MB:
#define OFF_QA   0L
#define OFF_QB   1048576L
#define OFF_QS   2097152L   // 2 splitK slabs for squarings
#define OFF_S    4194304L   // chain block: [z:4][a:32][o:10][d:1024]
#define OFF_R    5505024L   // sweep: [t:16][z:2][a*10+o:320][d:1024]
#define OFF_BSUM 15990784L
#define OFF_PART 16001024L  // part[j:512][b:64][o:10]

#define S_SLAB    327680L   // 32*10*1024 == 320*1024 (also R slab stride)
#define R_TSTRIDE 655360L

// ---------------- generic fp32 tiled GEMM ----------------
// C_slab_z[m,n] = sum_{k in chunk z} A_eff[m,k]*B[k,n],  K=N=1024, 64x64 tile,
// 256 thr, 4x4/thread. A_eff[m,k] = sum_{z<aSlabs} A[z*aSlabStride + m*1024 + k].
// Output slab z at C + z*cSlabStride (z = blockIdx.z, chunk = 1024/gridDim.z).
__global__ __launch_bounds__(256) void gemm_f32(
    const float* __restrict__ A, const float* __restrict__ B, float* __restrict__ C,
    int M, int aSlabs, long aSlabStride, long cSlabStride)
{
    __shared__ float As[16][68];   // [k][m], row 272B (16B-aligned)
    __shared__ float Bs[16][68];   // [k][n]
    const int tid = threadIdx.x;
    const int tx = tid & 15, ty = tid >> 4;
    const int bn = blockIdx.x * 64;
    const int bm = blockIdx.y * 64;
    const int kc = 1024 / gridDim.z;
    const int k0 = blockIdx.z * kc;
    const int lr = tid >> 2;            // A-load row 0..63
    const int lc = (tid & 3) << 2;      // A-load k4
    const int br = tid >> 4;            // B-load k row 0..15
    const int bc4 = (tid & 15) << 2;    // B-load n4
    float acc[4][4] = {};
    for (int kk = 0; kk < kc; kk += 16) {
        float4 av = make_float4(0.f, 0.f, 0.f, 0.f);
        int gm = bm + lr;
        if (gm < M) {
            const float* ap = A + (size_t)gm * 1024 + k0 + kk + lc;
            av = *(const float4*)ap;
            for (int z = 1; z < aSlabs; z++) {
                float4 t = *(const float4*)(ap + (size_t)z * aSlabStride);
                av.x += t.x; av.y += t.y; av.z += t.z; av.w += t.w;
            }
        }
        As[lc + 0][lr] = av.x; As[lc + 1][lr] = av.y;
        As[lc + 2][lr] = av.z; As[lc + 3][lr] = av.w;
        *(float4*)&Bs[br][bc4] =
            *(const float4*)(B + (size_t)(k0 + kk + br) * 1024 + bn + bc4);
        __syncthreads();
        #pragma unroll
        for (int k = 0; k < 16; k++) {
            float a4[4], b4[4];
            *(float4*)a4 = *(const float4*)&As[k][ty << 2];
            *(float4*)b4 = *(const float4*)&Bs[k][tx << 2];
            #pragma unroll
            for (int i = 0; i < 4; i++)
                #pragma unroll
                for (int j = 0; j < 4; j++)
                    acc[i][j] = fmaf(a4[i], b4[j], acc[i][j]);
        }
        __syncthreads();
    }
    float* Cz = C + (size_t)blockIdx.z * cSlabStride;
    #pragma unroll
    for (int i = 0; i < 4; i++) {
        int gm = bm + (ty << 2) + i;
        if (gm < M)
            *(float4*)(Cz + (size_t)gm * 1024 + bn + (tx << 2)) =
                make_float4(acc[i][0], acc[i][1], acc[i][2], acc[i][3]);
    }
}

// out[i] = in[i] + in[i+stride4]  (float4 units)
__global__ __launch_bounds__(256) void reduce2(
    const float4* __restrict__ in, float4* __restrict__ out, int n4, long stride4)
{
    int i = blockIdx.x * 256 + threadIdx.x;
    if (i < n4) {
        float4 a = in[i], b = in[i + stride4];
        out[i] = make_float4(a.x + b.x, a.y + b.y, a.z + b.z, a.w + b.w);
    }
}

// thin 10x1024 @ 1024x1024 chain step, k-split into 4 output slabs.
// grid (40 = 10 o * 4 dblk, 4 kz). A_eff = sum_{z<aSlabs} A[z*slabStride+...]
__global__ __launch_bounds__(256) void thin10(
    const float* __restrict__ A, const float* __restrict__ B, float* __restrict__ C,
    int aSlabs, long slabStride)
{
    int o = blockIdx.x >> 2;
    int d = ((blockIdx.x & 3) << 8) + threadIdx.x;
    int k0 = blockIdx.y << 8;
    float acc = 0.f;
    #pragma unroll 4
    for (int k = k0; k < k0 + 256; k++) {
        float a = A[o * 1024 + k];
        for (int z = 1; z < aSlabs; z++) a += A[(size_t)z * slabStride + o * 1024 + k];
        acc = fmaf(a, B[(size_t)k * 1024 + d], acc);
    }
    C[(size_t)blockIdx.y * slabStride + o * 1024 + d] = acc;
}

// In-place prefix Acc_M over R (slab0 <- Acc; reads slab0+slab1).
// bsum = 512*Wc + Sum_{M=1..511} Acc_M.  slot(m): t=(m-1)&15, a=(m-1)>>4.
__global__ __launch_bounds__(256) void prefix_acc(
    float* __restrict__ R, const float* __restrict__ Wc, float* __restrict__ bsum)
{
    int od = blockIdx.x * 256 + threadIdx.x;   // (o,d) 0..10239
    int o = od >> 10, d = od & 1023;
    float acc = 0.f, bac = 0.f;
    for (int m = 1; m <= 512; m++) {
        int t = (m - 1) & 15, a = (m - 1) >> 4;
        size_t idx = (size_t)t * R_TSTRIDE + (size_t)a * 10240 + (size_t)o * 1024 + d;
        acc += R[idx] + R[idx + S_SLAB];
        R[idx] = acc;
        if (m <= 511) bac += acc;
    }
    bsum[od] = 512.f * Wc[od] + bac;
}

// WG j: part[j][b][o] = Acc_{512-j}[o,:] . emb[x[b,j],:]
__global__ __launch_bounds__(320) void contract_k(
    const float* __restrict__ R, const int* __restrict__ x,
    const float* __restrict__ emb, float* __restrict__ part)
{
    __shared__ float Asm[10240];
    __shared__ float ev[2][1024];
    const int tid = threadIdx.x;
    const int j = blockIdx.x;
    const int m = 512 - j;
    const int t = (m - 1) & 15, a = (m - 1) >> 4;
    const float* Aptr = R + (size_t)t * R_TSTRIDE + (size_t)a * 10240; // slab0 = Acc
    for (int i = tid; i < 2560; i += 320)
        ((float4*)Asm)[i] = ((const float4*)Aptr)[i];
    if (tid < 256) {
        int idx0 = x[j];                              // b=0
        ((float4*)ev[0])[tid] = ((const float4*)(emb + (size_t)idx0 * 1024))[tid];
    }
    __syncthreads();
    const int o = tid >> 5, g = tid & 31;             // 10 o-groups x 32 lanes
    for (int b = 0; b < 64; b++) {
        if (b + 1 < 64 && tid < 256) {
            int idxn = x[(b + 1) * 512 + j];
            ((float4*)ev[(b + 1) & 1])[tid] =
                ((const float4*)(emb + (size_t)idxn * 1024))[tid];
        }
        const float4* e4 = (const float4*)ev[b & 1];
        const float4* a4 = (const float4*)(Asm + o * 1024);
        float pacc = 0.f;
        #pragma unroll
        for (int k = 0; k < 8; k++) {
            int d4 = g + (k << 5);
            float4 aa = a4[d4], ee = e4[d4];
            pacc = fmaf(aa.x, ee.x, pacc); pacc = fmaf(aa.y, ee.y, pacc);
            pacc = fmaf(aa.z, ee.z, pacc); pacc = fmaf(aa.w, ee.w, pacc);
        }
        for (int off = 16; off; off >>= 1) pacc += __shfl_down(pacc, off, 32);
        if (g == 0) part[(size_t)j * 640 + b * 10 + o] = pacc;
        __syncthreads();
    }
}

// reduce partials over j, add bias/bc, mean /512, CE over 10 classes, mean over 64.
__global__ __launch_bounds__(640) void finalize_k(
    const float* __restrict__ part, const float* __restrict__ bsum,
    const float* __restrict__ bvec, const float* __restrict__ bc,
    const int* __restrict__ label, float* __restrict__ out)
{
    __shared__ float pred[64][10];
    __shared__ float biasv[10];
    const int tid = threadIdx.x;
    {   // phase A: pred[b][o] = sum_j part[j][b][o]   (tid == b*10+o)
        float s = 0.f;
        for (int j = 0; j < 512; j++) s += part[(size_t)j * 640 + tid];
        pred[tid / 10][tid % 10] = s;
    }
    {   // phase B: biasv[o] = bsum[o,:] . b   (wave w == o)
        int o = tid >> 6, lane = tid & 63;
        float s = 0.f;
        for (int k = lane; k < 1024; k += 64) s = fmaf(bsum[o * 1024 + k], bvec[k], s);
        for (int off = 32; off; off >>= 1) s += __shfl_down(s, off, 64);
        if (lane == 0) biasv[o] = s;
    }
    __syncthreads();
    float myloss = 0.f;
    if (tid < 64) {
        int b = tid, lab = label[b];
        float v[10], mx = -1e30f;
        #pragma unroll
        for (int o = 0; o < 10; o++) {
            v[o] = (pred[b][o] + biasv[o]) * (1.f / 512.f) + bc[o];
            mx = fmaxf(mx, v[o]);
        }
        float se = 0.f, vl = 0.f;
        #pragma unroll
        for (int o = 0; o < 10; o++) {
            se += __expf(v[o] - mx);
            if (o == lab) vl = v[o];
        }
        myloss = (mx + __logf(se)) - vl;   // = -(logit[label] - lse)
        for (int off = 32; off; off >>= 1) myloss += __shfl_down(myloss, off, 64);
        if (tid == 0) out[0] = myloss * (1.f / 64.f);
    }
}

extern "C" void kernel_launch(void* const* d_in, const int* in_sizes, int n_in,
                              void* d_out, int out_size, void* d_ws, size_t ws_size,
                              hipStream_t stream) {
    const int*   x     = (const int*)d_in[0];
    const int*   label = (const int*)d_in[1];
    const float* emb   = (const float*)d_in[2];
    const float* W     = (const float*)d_in[3];
    const float* bvec  = (const float*)d_in[4];
    const float* Wc    = (const float*)d_in[5];
    const float* bc    = (const float*)d_in[6];
    float* ws   = (float*)d_ws;
    float* Qa   = ws + OFF_QA;
    float* Qb   = ws + OFF_QB;
    float* Qs   = ws + OFF_QS;
    float* S    = ws + OFF_S;
    float* R    = ws + OFF_R;
    float* bsum = ws + OFF_BSUM;
    float* part = ws + OFF_PART;
    float* out  = (float*)d_out;

    dim3 blk(256);
    dim3 gsq(16, 16, 2);
    // squarings: W^2->Qa, W^4->Qb, W^8->Qa, P=W^16->Qb (splitK=2 + reduce)
    gemm_f32<<<gsq, blk, 0, stream>>>(W,  W,  Qs, 1024, 1, 0L, 1048576L);
    reduce2<<<1024, 256, 0, stream>>>((const float4*)Qs, (float4*)Qa, 262144, 262144L);
    gemm_f32<<<gsq, blk, 0, stream>>>(Qa, Qa, Qs, 1024, 1, 0L, 1048576L);
    reduce2<<<1024, 256, 0, stream>>>((const float4*)Qs, (float4*)Qb, 262144, 262144L);
    gemm_f32<<<gsq, blk, 0, stream>>>(Qb, Qb, Qs, 1024, 1, 0L, 1048576L);
    reduce2<<<1024, 256, 0, stream>>>((const float4*)Qs, (float4*)Qa, 262144, 262144L);
    gemm_f32<<<gsq, blk, 0, stream>>>(Qa, Qa, Qs, 1024, 1, 0L, 1048576L);
    reduce2<<<1024, 256, 0, stream>>>((const float4*)Qs, (float4*)Qb, 262144, 262144L);
    // chain init: s_0 = Wc in slab0; zero slabs 1..3 of a=0 rows
    hipMemcpyAsync(S, Wc, 10 * 1024 * sizeof(float), hipMemcpyDeviceToDevice, stream);
    hipMemsetAsync(S + 1 * S_SLAB, 0, 10 * 1024 * sizeof(float), stream);
    hipMemsetAsync(S + 2 * S_SLAB, 0, 10 * 1024 * sizeof(float), stream);
    hipMemsetAsync(S + 3 * S_SLAB, 0, 10 * 1024 * sizeof(float), stream);
    // chain: s_a = s_{a-1} * P  (a = 1..31), 4 k-chunk output slabs each
    for (int a = 1; a < 32; a++)
        thin10<<<dim3(40, 4), 256, 0, stream>>>(S + (a - 1) * 10240L, Qb,
                                                S + a * 10240L, (a == 1) ? 1 : 4, S_SLAB);
    // sweep: R[t] = R[t-1] * W (t=0 reads the 4-slab S block as 320x1024)
    gemm_f32<<<dim3(16, 5, 2), blk, 0, stream>>>(S, W, R, 320, 4, S_SLAB, S_SLAB);
    for (int t = 1; t < 16; t++)
        gemm_f32<<<dim3(16, 5, 2), blk, 0, stream>>>(R + (t - 1) * R_TSTRIDE, W,
                                                     R + t * R_TSTRIDE, 320, 2,
                                                     S_SLAB, S_SLAB);
    prefix_acc<<<40, 256, 0, stream>>>(R, Wc, bsum);
    contract_k<<<512, 320, 0, stream>>>(R, x, emb, part);
    finalize_k<<<1, 640, 0, stream>>>(part, bsum, bvec, bc, label, out);
}

// Round 2
// 845.790 us; speedup vs baseline: 3.1797x; 3.1797x over previous
//
#include <hip/hip_runtime.h>

// x(64,512) -> emb(1024); h_i = (h_{i-1}+e_i)W^T + b; pred_mean = mean_i(Wc h_i + bc); CE.
// Restructured: r_m = Wc*W^m. pred_sum[b,o] = sum_j <Acc_{512-j}[o,:], e_{b,j}>
//   + <bsum[o,:], b>,  Acc_M = sum_{m<=M} r_m,  bsum = 512*Wc + sum_m (512-m) r_m.
// r_1..r_512 built by fused power-doubling: level k multiplies by W^(2^(k-2)) and
// squares it in the SAME GEMM (A = [Q_{k-2}; D_{k-2}], B = Q_{k-2}). Row r <-> m=r+1.
// Everything kept as 2 splitK slabs (summed on next consumer's load) - no reduce pass.
//
// ws layout (floats), total 15,182,464 = 60.7 MB (round-0 used 65.3 MB OK):
#define QS       1048576L    // Q slab stride (1024x1024)
#define RSLAB    5242880L    // R slab stride (5120 rows x 1024)
#define OFF_Q0   0L          // 2 slabs
#define OFF_Q1   2097152L    // 2 slabs
#define OFF_R    4194304L    // 2 slabs x 5120x1024; row (m-1)*10+o
#define OFF_CS   14680064L   // csum  [8][10240]
#define OFF_WP   14761984L   // wpart [8][10240]
#define OFF_BS   14843904L   // bsum  [10][1024]
#define OFF_PRED 14854144L   // pred  [64][10]
#define OFF_PART 14854784L   // part  [512][64][10]

__device__ __forceinline__ float4 f4add(float4 a, float4 b) {
    return make_float4(a.x + b.x, a.y + b.y, a.z + b.z, a.w + b.w);
}

// D0 = Wc * W  (10x1024) -> R rows 0..9, two K-half slabs (splitK=2 convention)
__global__ __launch_bounds__(256) void thin_d0(
    const float* __restrict__ Wc, const float* __restrict__ W, float* __restrict__ R)
{
    const int o = blockIdx.x >> 2;
    const int d = ((blockIdx.x & 3) << 8) + threadIdx.x;
    const int k0 = blockIdx.y << 9;
    float acc = 0.f;
    #pragma unroll 8
    for (int k = k0; k < k0 + 512; k++)
        acc = fmaf(Wc[o * 1024 + k], W[(size_t)k * 1024 + d], acc);
    R[(size_t)blockIdx.y * RSLAB + o * 1024 + d] = acc;
}

// Fused squaring+doubling GEMM. A rows [0,a1M) from A1 (Q, slab stride QS),
// rows [a1M,a1M+a2M) from A2 (R, slab stride RSLAB); both summed over their slab
// count on load. B summed over bS slabs (stride QS). Output: splitK z-slab; rows
// < a1M -> C1 (stride QS), else C2 (stride RSLAB). K=N=1024 fixed, kc=512.
// TM x 64 tile, 256 threads, (TM/16) x 4 per thread.
template<int TM>
__global__ __launch_bounds__(256) void gemm2(
    const float* __restrict__ A1, const float* __restrict__ A2,
    const float* __restrict__ B, float* __restrict__ C1, float* __restrict__ C2,
    int a1M, int a2M, int a1S, int a2S, int bS)
{
    constexpr int RT = TM / 16;
    __shared__ float As[16][TM + 4];   // [k][m]
    __shared__ float Bs[16][68];       // [k][n]
    const int tid = threadIdx.x;
    const int tx = tid & 15, ty = tid >> 4;
    const int bn = blockIdx.x * 64;
    const int bm = blockIdx.y * TM;
    const int k0 = blockIdx.z * 512;
    const int M = a1M + a2M;
    float acc[RT][4] = {};
    for (int kk = 0; kk < 512; kk += 16) {
        #pragma unroll
        for (int t = 0; t < TM / 64; t++) {
            const int idx = tid + t * 256;
            const int row = idx >> 2, kq = (idx & 3) << 2;
            const int gm = bm + row;
            float4 av = make_float4(0.f, 0.f, 0.f, 0.f);
            if (gm < M) {
                if (gm < a1M) {
                    const float* ap = A1 + (size_t)gm * 1024 + k0 + kk + kq;
                    av = *(const float4*)ap;
                    if (a1S == 2) av = f4add(av, *(const float4*)(ap + QS));
                } else {
                    const float* ap = A2 + (size_t)(gm - a1M) * 1024 + k0 + kk + kq;
                    av = *(const float4*)ap;
                    if (a2S == 2) av = f4add(av, *(const float4*)(ap + RSLAB));
                }
            }
            As[kq + 0][row] = av.x; As[kq + 1][row] = av.y;
            As[kq + 2][row] = av.z; As[kq + 3][row] = av.w;
        }
        {
            const int br = tid >> 4, bc4 = (tid & 15) << 2;
            const float* bp = B + (size_t)(k0 + kk + br) * 1024 + bn + bc4;
            float4 bv = *(const float4*)bp;
            if (bS == 2) bv = f4add(bv, *(const float4*)(bp + QS));
            *(float4*)&Bs[br][bc4] = bv;
        }
        __syncthreads();
        #pragma unroll
        for (int k = 0; k < 16; k++) {
            float a[RT], b4[4];
            #pragma unroll
            for (int q = 0; q < RT / 4; q++)
                *(float4*)&a[q * 4] = *(const float4*)&As[k][ty * RT + q * 4];
            *(float4*)b4 = *(const float4*)&Bs[k][tx << 2];
            #pragma unroll
            for (int i = 0; i < RT; i++)
                #pragma unroll
                for (int j = 0; j < 4; j++)
                    acc[i][j] = fmaf(a[i], b4[j], acc[i][j]);
        }
        __syncthreads();
    }
    #pragma unroll
    for (int i = 0; i < RT; i++) {
        const int gm = bm + ty * RT + i;
        const float4 v = make_float4(acc[i][0], acc[i][1], acc[i][2], acc[i][3]);
        if (gm < a1M)
            *(float4*)(C1 + (size_t)blockIdx.z * QS + (size_t)gm * 1024 + bn + (tx << 2)) = v;
        else if (gm < M)
            *(float4*)(C2 + (size_t)blockIdx.z * RSLAB + (size_t)(gm - a1M) * 1024 + bn + (tx << 2)) = v;
    }
}

// pass1: chunk sums (8 chunks of 64 m) + weighted sums sum (511-r)*v for bsum.
__global__ __launch_bounds__(256) void prefix_pass1(
    const float* __restrict__ R, float* __restrict__ csum, float* __restrict__ wpart)
{
    const int od = blockIdx.x * 256 + threadIdx.x;
    const int c = blockIdx.y;
    const float* p0 = R + (size_t)(c * 64) * 10240 + od;
    float cs = 0.f, wsv = 0.f;
    #pragma unroll 4
    for (int i = 0; i < 64; i++) {
        float v = p0[(size_t)i * 10240] + p0[(size_t)i * 10240 + RSLAB];
        cs += v;
        wsv += (float)(511 - (c * 64 + i)) * v;
    }
    csum[c * 10240 + od] = cs;
    wpart[c * 10240 + od] = wsv;
}

// pass2: write Acc_m (running prefix) into R slab1 in place (element-wise RMW safe).
__global__ __launch_bounds__(256) void prefix_pass2(
    float* __restrict__ R, const float* __restrict__ csum)
{
    const int od = blockIdx.x * 256 + threadIdx.x;
    const int c = blockIdx.y;
    float base = 0.f;
    #pragma unroll
    for (int c2 = 0; c2 < 8; c2++) {
        float t = csum[c2 * 10240 + od];
        base += (c2 < c) ? t : 0.f;
    }
    float run = base;
    float* p0 = R + (size_t)(c * 64) * 10240 + od;
    #pragma unroll 4
    for (int i = 0; i < 64; i++) {
        float v = p0[(size_t)i * 10240] + p0[(size_t)i * 10240 + RSLAB];
        run += v;
        p0[(size_t)i * 10240 + RSLAB] = run;
    }
}

// bsum = 512*Wc + sum_c wpart[c]
__global__ __launch_bounds__(256) void bsum_k(
    const float* __restrict__ wpart, const float* __restrict__ Wc, float* __restrict__ bsum)
{
    const int od = blockIdx.x * 256 + threadIdx.x;
    float s = 512.f * Wc[od];
    #pragma unroll
    for (int c = 0; c < 8; c++) s += wpart[c * 10240 + od];
    bsum[od] = s;
}

// WG j: part[j][b][o] = Acc_{512-j}[o,:] . emb[x[b,j],:]   (Acc = R slab1)
__global__ __launch_bounds__(320) void contract_k(
    const float* __restrict__ R, const int* __restrict__ x,
    const float* __restrict__ emb, float* __restrict__ part)
{
    __shared__ float Asm[10240];
    __shared__ float ev[2][1024];
    const int tid = threadIdx.x;
    const int j = blockIdx.x;
    const float* Aptr = R + RSLAB + (size_t)(511 - j) * 10240;  // Acc_{512-j}
    for (int i = tid; i < 2560; i += 320)
        ((float4*)Asm)[i] = ((const float4*)Aptr)[i];
    if (tid < 256) {
        int idx0 = x[j];                              // b=0
        ((float4*)ev[0])[tid] = ((const float4*)(emb + (size_t)idx0 * 1024))[tid];
    }
    __syncthreads();
    const int o = tid >> 5, g = tid & 31;             // 10 o-groups x 32 lanes
    for (int b = 0; b < 64; b++) {
        if (b + 1 < 64 && tid < 256) {
            int idxn = x[(b + 1) * 512 + j];
            ((float4*)ev[(b + 1) & 1])[tid] =
                ((const float4*)(emb + (size_t)idxn * 1024))[tid];
        }
        const float4* e4 = (const float4*)ev[b & 1];
        const float4* a4 = (const float4*)(Asm + o * 1024);
        float pacc = 0.f;
        #pragma unroll
        for (int k = 0; k < 8; k++) {
            int d4 = g + (k << 5);
            float4 aa = a4[d4], ee = e4[d4];
            pacc = fmaf(aa.x, ee.x, pacc); pacc = fmaf(aa.y, ee.y, pacc);
            pacc = fmaf(aa.z, ee.z, pacc); pacc = fmaf(aa.w, ee.w, pacc);
        }
        for (int off = 16; off; off >>= 1) pacc += __shfl_down(pacc, off, 32);
        if (g == 0) part[(size_t)j * 640 + b * 10 + o] = pacc;
        __syncthreads();
    }
}

// pred[out] = sum_j part[j][out], out = b*10+o. 16 lanes per output.
__global__ __launch_bounds__(256) void reduce_part(
    const float* __restrict__ part, float* __restrict__ pred)
{
    const int gid = blockIdx.x * 256 + threadIdx.x;
    const int out = gid >> 4, s = gid & 15;
    float p = 0.f;
    #pragma unroll 8
    for (int t = 0; t < 32; t++) p += part[(size_t)(s + (t << 4)) * 640 + out];
    for (int off = 8; off; off >>= 1) p += __shfl_down(p, off, 16);
    if (s == 0) pred[out] = p;
}

// biasv[o] = bsum[o,:].b ; logits = (pred+biasv)/512 + bc ; CE mean over batch.
__global__ __launch_bounds__(640) void finalize_k(
    const float* __restrict__ pred, const float* __restrict__ bsum,
    const float* __restrict__ bvec, const float* __restrict__ bc,
    const int* __restrict__ label, float* __restrict__ out)
{
    __shared__ float biasv[10];
    const int tid = threadIdx.x;
    {
        int o = tid >> 6, lane = tid & 63;
        float s = 0.f;
        for (int k = lane; k < 1024; k += 64) s = fmaf(bsum[o * 1024 + k], bvec[k], s);
        for (int off = 32; off; off >>= 1) s += __shfl_down(s, off, 64);
        if (lane == 0) biasv[o] = s;
    }
    __syncthreads();
    if (tid < 64) {
        int b = tid, lab = label[b];
        float v[10], mx = -1e30f;
        #pragma unroll
        for (int o = 0; o < 10; o++) {
            v[o] = (pred[b * 10 + o] + biasv[o]) * (1.f / 512.f) + bc[o];
            mx = fmaxf(mx, v[o]);
        }
        float se = 0.f, vl = 0.f;
        #pragma unroll
        for (int o = 0; o < 10; o++) {
            se += __expf(v[o] - mx);
            if (o == lab) vl = v[o];
        }
        float myloss = (mx + __logf(se)) - vl;
        for (int off = 32; off; off >>= 1) myloss += __shfl_down(myloss, off, 64);
        if (tid == 0) out[0] = myloss * (1.f / 64.f);
    }
}

extern "C" void kernel_launch(void* const* d_in, const int* in_sizes, int n_in,
                              void* d_out, int out_size, void* d_ws, size_t ws_size,
                              hipStream_t stream) {
    const int*   x     = (const int*)d_in[0];
    const int*   label = (const int*)d_in[1];
    const float* emb   = (const float*)d_in[2];
    const float* W     = (const float*)d_in[3];
    const float* bvec  = (const float*)d_in[4];
    const float* Wc    = (const float*)d_in[5];
    const float* bc    = (const float*)d_in[6];
    float* ws    = (float*)d_ws;
    float* Q0    = ws + OFF_Q0;
    float* Q1v   = ws + OFF_Q1;
    float* R     = ws + OFF_R;
    float* csum  = ws + OFF_CS;
    float* wpart = ws + OFF_WP;
    float* bsum  = ws + OFF_BS;
    float* pred  = ws + OFF_PRED;
    float* part  = ws + OFF_PART;
    float* out   = (float*)d_out;

    // level 1: D0 = Wc*W (rows m=1)
    thin_d0<<<dim3(40, 2), 256, 0, stream>>>(Wc, W, R);
    // levels 2..10: B = W^(2^(k-2)); fused [square B ; extend D rows]
    const float* Qp = W;   // Q_{k-2}
    float* Qn = Q0;
    int a1S = 1, bS = 1;
    long a2rows = 10;
    for (int k = 2; k <= 10; k++) {
        int a1M = (k <= 9) ? 1024 : 0;         // last level: no squaring needed
        int a2M = (int)a2rows;
        float* C2 = R + a2rows * 1024;         // new D rows at offset a2rows
        int M = a1M + a2M;
        if (M < 2048)
            gemm2<64><<<dim3(16, (M + 63) / 64, 2), 256, 0, stream>>>(
                Qp, R, Qp, Qn, C2, a1M, a2M, a1S, 2, bS);
        else
            gemm2<128><<<dim3(16, (M + 127) / 128, 2), 256, 0, stream>>>(
                Qp, R, Qp, Qn, C2, a1M, a2M, a1S, 2, bS);
        Qp = Qn; Qn = (Qn == Q0) ? Q1v : Q0;
        a1S = 2; bS = 2;
        a2rows <<= 1;
    }
    prefix_pass1<<<dim3(40, 8), 256, 0, stream>>>(R, csum, wpart);
    prefix_pass2<<<dim3(40, 8), 256, 0, stream>>>(R, csum);
    bsum_k<<<40, 256, 0, stream>>>(wpart, Wc, bsum);
    contract_k<<<512, 320, 0, stream>>>(R, x, emb, part);
    reduce_part<<<40, 256, 0, stream>>>(part, pred);
    finalize_k<<<1, 640, 0, stream>>>(pred, bsum, bvec, bc, label, out);
}

// Round 3
// 784.256 us; speedup vs baseline: 3.4292x; 1.0785x over previous
//
#include <hip/hip_runtime.h>

// x(64,512) -> emb(1024); h_i = (h_{i-1}+e_i)W^T + b; pred_mean = mean_i(Wc h_i + bc); CE.
// r_m = Wc*(stored W)^m. pred_sum[b,o] = sum_j <Acc_{512-j}[o,:], e_{b,j}> + <bsum[o,:],b>
//   Acc_M = sum_{m<=M} r_m,  bsum = 512*Wc + sum_m (512-m) r_m.
// Power-doubling levels k=2..10: B=W^(2^(k-2)); one MFMA GEMM squares B (rows<1024)
// and extends D rows (A2 = R rows 0..a2M) simultaneously. All matrices stored as
// SPLIT-BF16 (hi+lo); products via 3 MFMA passes (hh + lh + hl), fp32 accumulate.
// R row (m-1)*10+o. prefix reconstructs fp32 as hi+lo.
//
// ws layout: fp32 region then u16 region; total 60,729,856 B (== round-2 size, safe).
#define OFF_ACC  0L          // Acc fp32 [5120][1024]
#define OFF_CS   5242880L    // csum [8][10240]
#define OFF_WP   5324800L    // wpart [8][10240]
#define OFF_BS   5406720L    // bsum [10][1024]
#define OFF_PRED 5416960L    // pred [640]
#define OFF_PART 5417600L    // part [512][64][10]
#define OFF_U16  5745280L    // u16 region base (float index; 64B aligned)
// u16 offsets within region:
#define UQAH 0L
#define UQAL 1048576L
#define UQATH 2097152L
#define UQATL 3145728L
#define UQBH 4194304L
#define UQBL 5242880L
#define UQBTH 6291456L
#define UQBTL 7340032L
#define URH  8388608L        // Rh [5120][1024]
#define URL  13631488L       // Rl [5120][1024]

typedef unsigned short u16;
typedef unsigned int u32;
typedef u16 us8 __attribute__((ext_vector_type(8)));
typedef short s8v __attribute__((ext_vector_type(8)));
typedef float f4v __attribute__((ext_vector_type(4)));

__device__ __forceinline__ u16 f2b(float f) {       // fp32 -> bf16 RNE (finite)
    u32 u = __float_as_uint(f);
    return (u16)((u + 0x7fffu + ((u >> 16) & 1u)) >> 16);
}
__device__ __forceinline__ float b2f(u16 h) {
    return __uint_as_float((u32)h << 16);
}

// ---- split W (fp32) into bf16 hi/lo, plus transposed copies (LDS 64x64 tile) ----
__global__ __launch_bounds__(256) void split_w(
    const float* __restrict__ W, u16* __restrict__ Qh, u16* __restrict__ Ql,
    u16* __restrict__ QTh, u16* __restrict__ QTl)
{
    __shared__ u32 T[64][65];
    const int tid = threadIdx.x;
    const int r = tid >> 2, c0 = (tid & 3) << 4;
    alignas(16) u16 h[16], l[16];
    const size_t src = (size_t)(blockIdx.y * 64 + r) * 1024 + blockIdx.x * 64 + c0;
    #pragma unroll
    for (int q = 0; q < 4; q++) {
        float4 v = *(const float4*)(W + src + q * 4);
        float vv[4] = {v.x, v.y, v.z, v.w};
        #pragma unroll
        for (int i = 0; i < 4; i++) {
            u16 hh = f2b(vv[i]);
            u16 ll = f2b(vv[i] - b2f(hh));
            h[q * 4 + i] = hh; l[q * 4 + i] = ll;
            T[c0 + q * 4 + i][r] = ((u32)ll << 16) | hh;
        }
    }
    *(us8*)(Qh + src) = *(const us8*)&h[0];
    *(us8*)(Qh + src + 8) = *(const us8*)&h[8];
    *(us8*)(Ql + src) = *(const us8*)&l[0];
    *(us8*)(Ql + src + 8) = *(const us8*)&l[8];
    __syncthreads();
    alignas(16) u16 th[16], tl[16];
    #pragma unroll
    for (int i = 0; i < 16; i++) {
        u32 v = T[r][c0 + i];
        th[i] = (u16)(v & 0xffffu); tl[i] = (u16)(v >> 16);
    }
    const size_t dst = (size_t)(blockIdx.x * 64 + r) * 1024 + blockIdx.y * 64 + c0;
    *(us8*)(QTh + dst) = *(const us8*)&th[0];
    *(us8*)(QTh + dst + 8) = *(const us8*)&th[8];
    *(us8*)(QTl + dst) = *(const us8*)&tl[0];
    *(us8*)(QTl + dst + 8) = *(const us8*)&tl[8];
}

// ---- transpose a bf16 hi/lo matrix pair (for next level's B operand) ----
__global__ __launch_bounds__(256) void transp_q(
    const u16* __restrict__ Qh, const u16* __restrict__ Ql,
    u16* __restrict__ QTh, u16* __restrict__ QTl)
{
    __shared__ u32 T[64][65];
    const int tid = threadIdx.x;
    const int r = tid >> 2, c0 = (tid & 3) << 4;
    const size_t src = (size_t)(blockIdx.y * 64 + r) * 1024 + blockIdx.x * 64 + c0;
    us8 h0 = *(const us8*)(Qh + src), h1 = *(const us8*)(Qh + src + 8);
    us8 l0 = *(const us8*)(Ql + src), l1 = *(const us8*)(Ql + src + 8);
    #pragma unroll
    for (int i = 0; i < 8; i++) {
        T[c0 + i][r] = ((u32)l0[i] << 16) | h0[i];
        T[c0 + 8 + i][r] = ((u32)l1[i] << 16) | h1[i];
    }
    __syncthreads();
    alignas(16) u16 th[16], tl[16];
    #pragma unroll
    for (int i = 0; i < 16; i++) {
        u32 v = T[r][c0 + i];
        th[i] = (u16)(v & 0xffffu); tl[i] = (u16)(v >> 16);
    }
    const size_t dst = (size_t)(blockIdx.x * 64 + r) * 1024 + blockIdx.y * 64 + c0;
    *(us8*)(QTh + dst) = *(const us8*)&th[0];
    *(us8*)(QTh + dst + 8) = *(const us8*)&th[8];
    *(us8*)(QTl + dst) = *(const us8*)&tl[0];
    *(us8*)(QTl + dst + 8) = *(const us8*)&tl[8];
}

// ---- D0 = Wc*W (10x1024) -> R rows 0..9 as bf16 hi/lo (fp32 vector compute) ----
__global__ __launch_bounds__(256) void thin_d0(
    const float* __restrict__ Wc, const float* __restrict__ W,
    u16* __restrict__ Rh, u16* __restrict__ Rl)
{
    const int o = blockIdx.x >> 2;
    const int d = ((blockIdx.x & 3) << 8) + threadIdx.x;
    float acc = 0.f;
    #pragma unroll 8
    for (int k = 0; k < 1024; k++)
        acc = fmaf(Wc[o * 1024 + k], W[(size_t)k * 1024 + d], acc);
    u16 h = f2b(acc);
    Rh[o * 1024 + d] = h;
    Rl[o * 1024 + d] = f2b(acc - b2f(h));
}

// ---- split-bf16 MFMA GEMM: C = A_eff * B,  K=N=1024.
// A rows [0,a1M) from Q(hi/lo); rows [a1M,M) from R rows 0..a2M (D_prev).
// B supplied TRANSPOSED (BT[n][k]) so b-frags read rows. 128x128 tile, 4 waves,
// each wave 4x4 16x16x32 tiles, 3 MFMA passes (hh, lh, hl). Output rows<a1M ->
// Qo hi/lo; else R rows a2M+(gr-a1M). LDS frag-native layout [kq][row][8].
__global__ __launch_bounds__(256) void gemm_mfma(
    const u16* __restrict__ Ah_g, const u16* __restrict__ Al_g,
    const u16* __restrict__ Rh_g, const u16* __restrict__ Rl_g,
    const u16* __restrict__ BTh_g, const u16* __restrict__ BTl_g,
    u16* __restrict__ Qoh, u16* __restrict__ Qol,
    u16* __restrict__ Roh, u16* __restrict__ Rol,
    int a1M, int a2M)
{
    const int M = a1M + a2M;
    __shared__ alignas(16) u16 Ash[4][129][8], Asl[4][129][8];
    __shared__ alignas(16) u16 Bsh[4][129][8], Bsl[4][129][8];
    const int tid = threadIdx.x;
    const int bn = blockIdx.x << 7, bm = blockIdx.y << 7;
    const int lane = tid & 63, wid = tid >> 6;
    const int wm = (wid & 1) << 6, wn = (wid >> 1) << 6;
    const int lrow = lane & 15, kq = lane >> 4;
    const int srow = tid >> 1;              // staging row 0..127
    const int skq = (tid & 1) << 1;         // staging kq planes {0,1} or {2,3}
    const int sk = skq << 3;                // k offset 0 or 16
    f4v acc[4][4];
    #pragma unroll
    for (int i = 0; i < 4; i++)
        #pragma unroll
        for (int j = 0; j < 4; j++) acc[i][j] = 0.f;

    for (int k0 = 0; k0 < 1024; k0 += 32) {
        // ---- stage A (with row guard; zeros past M) ----
        us8 h0 = 0, h1 = 0, l0 = 0, l1 = 0;
        const int gm = bm + srow;
        const u16* ph = nullptr; const u16* pl = nullptr;
        if (gm < a1M) {
            ph = Ah_g + (size_t)gm * 1024 + k0 + sk;
            pl = Al_g + (size_t)gm * 1024 + k0 + sk;
        } else if (gm < M) {
            ph = Rh_g + (size_t)(gm - a1M) * 1024 + k0 + sk;
            pl = Rl_g + (size_t)(gm - a1M) * 1024 + k0 + sk;
        }
        if (ph) {
            h0 = *(const us8*)ph; h1 = *(const us8*)(ph + 8);
            l0 = *(const us8*)pl; l1 = *(const us8*)(pl + 8);
        }
        *(us8*)&Ash[skq][srow][0] = h0;
        *(us8*)&Ash[skq + 1][srow][0] = h1;
        *(us8*)&Asl[skq][srow][0] = l0;
        *(us8*)&Asl[skq + 1][srow][0] = l1;
        // ---- stage B (BT rows bn..bn+127, no guard) ----
        {
            const u16* pbh = BTh_g + (size_t)(bn + srow) * 1024 + k0 + sk;
            const u16* pbl = BTl_g + (size_t)(bn + srow) * 1024 + k0 + sk;
            us8 b0 = *(const us8*)pbh, b1 = *(const us8*)(pbh + 8);
            us8 c0 = *(const us8*)pbl, c1 = *(const us8*)(pbl + 8);
            *(us8*)&Bsh[skq][srow][0] = b0;
            *(us8*)&Bsh[skq + 1][srow][0] = b1;
            *(us8*)&Bsl[skq][srow][0] = c0;
            *(us8*)&Bsl[skq + 1][srow][0] = c1;
        }
        __syncthreads();
        // ---- fragments + MFMA ----
        s8v afh[4], afl[4], bfh[4], bfl[4];
        #pragma unroll
        for (int i = 0; i < 4; i++) {
            afh[i] = *(const s8v*)&Ash[kq][wm + (i << 4) + lrow][0];
            afl[i] = *(const s8v*)&Asl[kq][wm + (i << 4) + lrow][0];
            bfh[i] = *(const s8v*)&Bsh[kq][wn + (i << 4) + lrow][0];
            bfl[i] = *(const s8v*)&Bsl[kq][wn + (i << 4) + lrow][0];
        }
        #pragma unroll
        for (int mi = 0; mi < 4; mi++)
            #pragma unroll
            for (int ni = 0; ni < 4; ni++) {
                acc[mi][ni] = __builtin_amdgcn_mfma_f32_16x16x32_bf16(
                    afh[mi], bfh[ni], acc[mi][ni], 0, 0, 0);
                acc[mi][ni] = __builtin_amdgcn_mfma_f32_16x16x32_bf16(
                    afl[mi], bfh[ni], acc[mi][ni], 0, 0, 0);
                acc[mi][ni] = __builtin_amdgcn_mfma_f32_16x16x32_bf16(
                    afh[mi], bfl[ni], acc[mi][ni], 0, 0, 0);
            }
        __syncthreads();
    }
    // ---- epilogue: split to hi/lo, route Q-part / D-part ----
    // C/D layout (m89-verified): col = lane&15, row = (lane>>4)*4 + reg.
    #pragma unroll
    for (int mi = 0; mi < 4; mi++) {
        #pragma unroll
        for (int i = 0; i < 4; i++) {
            const int gr = bm + wm + (mi << 4) + (kq << 2) + i;
            if (gr >= M) continue;
            u16* oh; u16* ol; size_t base;
            if (gr < a1M) { oh = Qoh; ol = Qol; base = (size_t)gr * 1024; }
            else { oh = Roh; ol = Rol; base = (size_t)(gr - a1M + a2M) * 1024; }
            #pragma unroll
            for (int ni = 0; ni < 4; ni++) {
                const float v = acc[mi][ni][i];
                const u16 hh = f2b(v);
                const size_t idx = base + bn + wn + (ni << 4) + lrow;
                oh[idx] = hh;
                ol[idx] = f2b(v - b2f(hh));
            }
        }
    }
}

// ---- prefix pass1: chunk sums + weighted sums (v = hi+lo) ----
__global__ __launch_bounds__(256) void prefix_pass1(
    const u16* __restrict__ Rh, const u16* __restrict__ Rl,
    float* __restrict__ csum, float* __restrict__ wpart)
{
    const int od = blockIdx.x * 256 + threadIdx.x;
    const int c = blockIdx.y;
    const u16* ph = Rh + (size_t)(c * 64) * 10240 + od;
    const u16* pl = Rl + (size_t)(c * 64) * 10240 + od;
    float cs = 0.f, wsv = 0.f;
    #pragma unroll 4
    for (int i = 0; i < 64; i++) {
        float v = b2f(ph[(size_t)i * 10240]) + b2f(pl[(size_t)i * 10240]);
        cs += v;
        wsv += (float)(511 - (c * 64 + i)) * v;
    }
    csum[c * 10240 + od] = cs;
    wpart[c * 10240 + od] = wsv;
}

// ---- prefix pass2: Acc_m (fp32) from running prefix ----
__global__ __launch_bounds__(256) void prefix_pass2(
    const u16* __restrict__ Rh, const u16* __restrict__ Rl,
    const float* __restrict__ csum, float* __restrict__ Acc)
{
    const int od = blockIdx.x * 256 + threadIdx.x;
    const int c = blockIdx.y;
    float run = 0.f;
    #pragma unroll
    for (int c2 = 0; c2 < 8; c2++) {
        float t = csum[c2 * 10240 + od];
        run += (c2 < c) ? t : 0.f;
    }
    const u16* ph = Rh + (size_t)(c * 64) * 10240 + od;
    const u16* pl = Rl + (size_t)(c * 64) * 10240 + od;
    float* pa = Acc + (size_t)(c * 64) * 10240 + od;
    #pragma unroll 4
    for (int i = 0; i < 64; i++) {
        run += b2f(ph[(size_t)i * 10240]) + b2f(pl[(size_t)i * 10240]);
        pa[(size_t)i * 10240] = run;
    }
}

__global__ __launch_bounds__(256) void bsum_k(
    const float* __restrict__ wpart, const float* __restrict__ Wc, float* __restrict__ bsum)
{
    const int od = blockIdx.x * 256 + threadIdx.x;
    float s = 512.f * Wc[od];
    #pragma unroll
    for (int c = 0; c < 8; c++) s += wpart[c * 10240 + od];
    bsum[od] = s;
}

// ---- WG j: part[j][b][o] = Acc_{512-j}[o,:] . emb[x[b,j],:] ----
__global__ __launch_bounds__(320) void contract_k(
    const float* __restrict__ Acc, const int* __restrict__ x,
    const float* __restrict__ emb, float* __restrict__ part)
{
    __shared__ float Asm[10240];
    __shared__ float ev[2][1024];
    const int tid = threadIdx.x;
    const int j = blockIdx.x;
    const float* Aptr = Acc + (size_t)(511 - j) * 10240;
    for (int i = tid; i < 2560; i += 320)
        ((float4*)Asm)[i] = ((const float4*)Aptr)[i];
    if (tid < 256) {
        int idx0 = x[j];
        ((float4*)ev[0])[tid] = ((const float4*)(emb + (size_t)idx0 * 1024))[tid];
    }
    __syncthreads();
    const int o = tid >> 5, g = tid & 31;
    for (int b = 0; b < 64; b++) {
        if (b + 1 < 64 && tid < 256) {
            int idxn = x[(b + 1) * 512 + j];
            ((float4*)ev[(b + 1) & 1])[tid] =
                ((const float4*)(emb + (size_t)idxn * 1024))[tid];
        }
        const float4* e4 = (const float4*)ev[b & 1];
        const float4* a4 = (const float4*)(Asm + o * 1024);
        float pacc = 0.f;
        #pragma unroll
        for (int k = 0; k < 8; k++) {
            int d4 = g + (k << 5);
            float4 aa = a4[d4], ee = e4[d4];
            pacc = fmaf(aa.x, ee.x, pacc); pacc = fmaf(aa.y, ee.y, pacc);
            pacc = fmaf(aa.z, ee.z, pacc); pacc = fmaf(aa.w, ee.w, pacc);
        }
        for (int off = 16; off; off >>= 1) pacc += __shfl_down(pacc, off, 32);
        if (g == 0) part[(size_t)j * 640 + b * 10 + o] = pacc;
        __syncthreads();
    }
}

__global__ __launch_bounds__(256) void reduce_part(
    const float* __restrict__ part, float* __restrict__ pred)
{
    const int gid = blockIdx.x * 256 + threadIdx.x;
    const int out = gid >> 4, s = gid & 15;
    float p = 0.f;
    #pragma unroll 8
    for (int t = 0; t < 32; t++) p += part[(size_t)(s + (t << 4)) * 640 + out];
    for (int off = 8; off; off >>= 1) p += __shfl_down(p, off, 16);
    if (s == 0) pred[out] = p;
}

__global__ __launch_bounds__(640) void finalize_k(
    const float* __restrict__ pred, const float* __restrict__ bsum,
    const float* __restrict__ bvec, const float* __restrict__ bc,
    const int* __restrict__ label, float* __restrict__ out)
{
    __shared__ float biasv[10];
    const int tid = threadIdx.x;
    {
        int o = tid >> 6, lane = tid & 63;
        float s = 0.f;
        for (int k = lane; k < 1024; k += 64) s = fmaf(bsum[o * 1024 + k], bvec[k], s);
        for (int off = 32; off; off >>= 1) s += __shfl_down(s, off, 64);
        if (lane == 0) biasv[o] = s;
    }
    __syncthreads();
    if (tid < 64) {
        int b = tid, lab = label[b];
        float v[10], mx = -1e30f;
        #pragma unroll
        for (int o = 0; o < 10; o++) {
            v[o] = (pred[b * 10 + o] + biasv[o]) * (1.f / 512.f) + bc[o];
            mx = fmaxf(mx, v[o]);
        }
        float se = 0.f, vl = 0.f;
        #pragma unroll
        for (int o = 0; o < 10; o++) {
            se += __expf(v[o] - mx);
            if (o == lab) vl = v[o];
        }
        float myloss = (mx + __logf(se)) - vl;
        for (int off = 32; off; off >>= 1) myloss += __shfl_down(myloss, off, 64);
        if (tid == 0) out[0] = myloss * (1.f / 64.f);
    }
}

extern "C" void kernel_launch(void* const* d_in, const int* in_sizes, int n_in,
                              void* d_out, int out_size, void* d_ws, size_t ws_size,
                              hipStream_t stream) {
    const int*   x     = (const int*)d_in[0];
    const int*   label = (const int*)d_in[1];
    const float* emb   = (const float*)d_in[2];
    const float* W     = (const float*)d_in[3];
    const float* bvec  = (const float*)d_in[4];
    const float* Wc    = (const float*)d_in[5];
    const float* bc    = (const float*)d_in[6];
    float* ws    = (float*)d_ws;
    float* Acc   = ws + OFF_ACC;
    float* csum  = ws + OFF_CS;
    float* wpart = ws + OFF_WP;
    float* bsum  = ws + OFF_BS;
    float* pred  = ws + OFF_PRED;
    float* part  = ws + OFF_PART;
    u16*   ub    = (u16*)(ws + OFF_U16);
    u16* RH = ub + URH;
    u16* RL = ub + URL;
    u16* qin[4]  = {ub + UQAH, ub + UQAL, ub + UQATH, ub + UQATL};
    u16* qout[4] = {ub + UQBH, ub + UQBL, ub + UQBTH, ub + UQBTL};
    float* out   = (float*)d_out;

    split_w<<<dim3(16, 16), 256, 0, stream>>>(W, qin[0], qin[1], qin[2], qin[3]);
    thin_d0<<<40, 256, 0, stream>>>(Wc, W, RH, RL);

    int a2M = 10;
    for (int k = 2; k <= 10; k++) {
        const int a1M = (k < 10) ? 1024 : 0;
        const int M = a1M + a2M;
        dim3 g(8, (M + 127) / 128);
        gemm_mfma<<<g, 256, 0, stream>>>(qin[0], qin[1], RH, RL, qin[2], qin[3],
                                         qout[0], qout[1], RH, RL, a1M, a2M);
        if (k < 10)
            transp_q<<<dim3(16, 16), 256, 0, stream>>>(qout[0], qout[1], qout[2], qout[3]);
        for (int i = 0; i < 4; i++) { u16* t = qin[i]; qin[i] = qout[i]; qout[i] = t; }
        a2M <<= 1;
    }

    prefix_pass1<<<dim3(40, 8), 256, 0, stream>>>(RH, RL, csum, wpart);
    prefix_pass2<<<dim3(40, 8), 256, 0, stream>>>(RH, RL, csum, Acc);
    bsum_k<<<40, 256, 0, stream>>>(wpart, Wc, bsum);
    contract_k<<<512, 320, 0, stream>>>(Acc, x, emb, part);
    reduce_part<<<40, 256, 0, stream>>>(part, pred);
    finalize_k<<<1, 640, 0, stream>>>(pred, bsum, bvec, bc, label, out);
}

// Round 4
// 522.319 us; speedup vs baseline: 5.1489x; 1.5015x over previous
//
#include <hip/hip_runtime.h>

// x(64,512) -> emb(1024); h_i = (h_{i-1}+e_i)W^T + b; pred_mean = mean_i(Wc h_i + bc); CE.
// r_m = Wc*(stored W)^m. pred_sum[b,o] = sum_j <Acc_{512-j}[o,:], e_{b,j}> + <bsum[o,:],b>
//   Acc_M = sum_{m<=M} r_m,  bsum = 512*Wc + sum_m (512-m) r_m.
// Power-doubling levels k=2..10: one MFMA GEMM squares Q (rows<1024) and extends D
// rows; split-bf16 (hi/lo), 3 MFMA passes. v4: GEMM is split-K (fp32 C partials),
// combine kernel sums slabs + emits hi/lo + fused transpose (replaces transp_q).
//
// ws (floats): C/Acc overlay 5,636,096 | csum 81920 | wpart 81920 | bsum 10240 |
// pred 640 | part 327680 | then u16 region. Total 62.3 MB (< proven-safe 65.3 MB).
#define OFF_C    0L
#define OFF_CS   5636096L
#define OFF_WP   5718016L
#define OFF_BS   5799936L
#define OFF_PRED 5810176L
#define OFF_PART 5810816L
#define OFF_U16  6138496L
// u16 offsets:
#define UQAH 0L
#define UQAL 1048576L
#define UQATH 2097152L
#define UQATL 3145728L
#define UQBH 4194304L
#define UQBL 5242880L
#define UQBTH 6291456L
#define UQBTL 7340032L
#define URH  8388608L
#define URL  13631488L
#define CS4  1409024L    // C slab stride for zsplit=4 (1376 rows)
#define CS2  2621440L    // C slab stride for zsplit=2 (2560 rows)

typedef unsigned short u16;
typedef unsigned int u32;
typedef u16 us8 __attribute__((ext_vector_type(8)));
typedef short s8v __attribute__((ext_vector_type(8)));
typedef float f4v __attribute__((ext_vector_type(4)));

__device__ __forceinline__ u16 f2b(float f) {
    u32 u = __float_as_uint(f);
    return (u16)((u + 0x7fffu + ((u >> 16) & 1u)) >> 16);
}
__device__ __forceinline__ float b2f(u16 h) {
    return __uint_as_float((u32)h << 16);
}

// ---- split W (fp32) into bf16 hi/lo + transposed copies ----
__global__ __launch_bounds__(256) void split_w(
    const float* __restrict__ W, u16* __restrict__ Qh, u16* __restrict__ Ql,
    u16* __restrict__ QTh, u16* __restrict__ QTl)
{
    __shared__ u32 T[64][65];
    const int tid = threadIdx.x;
    const int r = tid >> 2, c0 = (tid & 3) << 4;
    alignas(16) u16 h[16], l[16];
    const size_t src = (size_t)(blockIdx.y * 64 + r) * 1024 + blockIdx.x * 64 + c0;
    #pragma unroll
    for (int q = 0; q < 4; q++) {
        float4 v = *(const float4*)(W + src + q * 4);
        float vv[4] = {v.x, v.y, v.z, v.w};
        #pragma unroll
        for (int i = 0; i < 4; i++) {
            u16 hh = f2b(vv[i]);
            u16 ll = f2b(vv[i] - b2f(hh));
            h[q * 4 + i] = hh; l[q * 4 + i] = ll;
            T[c0 + q * 4 + i][r] = ((u32)ll << 16) | hh;
        }
    }
    *(us8*)(Qh + src) = *(const us8*)&h[0];
    *(us8*)(Qh + src + 8) = *(const us8*)&h[8];
    *(us8*)(Ql + src) = *(const us8*)&l[0];
    *(us8*)(Ql + src + 8) = *(const us8*)&l[8];
    __syncthreads();
    alignas(16) u16 th[16], tl[16];
    #pragma unroll
    for (int i = 0; i < 16; i++) {
        u32 v = T[r][c0 + i];
        th[i] = (u16)(v & 0xffffu); tl[i] = (u16)(v >> 16);
    }
    const size_t dst = (size_t)(blockIdx.x * 64 + r) * 1024 + blockIdx.y * 64 + c0;
    *(us8*)(QTh + dst) = *(const us8*)&th[0];
    *(us8*)(QTh + dst + 8) = *(const us8*)&th[8];
    *(us8*)(QTl + dst) = *(const us8*)&tl[0];
    *(us8*)(QTl + dst + 8) = *(const us8*)&tl[8];
}

// ---- D0 = Wc*W partials (k-split by 8) -> pbuf[kz][10240] ----
__global__ __launch_bounds__(256) void thin_d0(
    const float* __restrict__ Wc, const float* __restrict__ W, float* __restrict__ pbuf)
{
    const int o = blockIdx.x >> 2;
    const int d = ((blockIdx.x & 3) << 8) + threadIdx.x;
    const int k0 = blockIdx.y << 7;
    float acc = 0.f;
    #pragma unroll 8
    for (int k = k0; k < k0 + 128; k++)
        acc = fmaf(Wc[o * 1024 + k], W[(size_t)k * 1024 + d], acc);
    pbuf[(size_t)blockIdx.y * 10240 + o * 1024 + d] = acc;
}

__global__ __launch_bounds__(256) void d0_fin(
    const float* __restrict__ pbuf, u16* __restrict__ Rh, u16* __restrict__ Rl)
{
    const int od = blockIdx.x * 256 + threadIdx.x;
    float v = 0.f;
    #pragma unroll
    for (int z = 0; z < 8; z++) v += pbuf[(size_t)z * 10240 + od];
    u16 h = f2b(v);
    Rh[od] = h;
    Rl[od] = f2b(v - b2f(h));
}

// ---- split-bf16 MFMA GEMM, split-K, fp32 partial output ----
// A rows [0,a1M) from Q(hi/lo); rows [a1M,M) from R rows 0..a2M. B transposed.
// 128x128 tile, 4 waves, 4x4 16x16x32 each, 3 passes. Register-prefetch pipeline.
// C[z][gr][1024] fp32, slab stride cS, z = blockIdx.z over kc-chunks.
__global__ __launch_bounds__(256) void gemm_mfma(
    const u16* __restrict__ Ah_g, const u16* __restrict__ Al_g,
    const u16* __restrict__ Rh_g, const u16* __restrict__ Rl_g,
    const u16* __restrict__ BTh_g, const u16* __restrict__ BTl_g,
    float* __restrict__ C, int a1M, int a2M, int kc, long cS)
{
    const int M = a1M + a2M;
    __shared__ alignas(16) u16 Ash[4][129][8], Asl[4][129][8];
    __shared__ alignas(16) u16 Bsh[4][129][8], Bsl[4][129][8];
    const int tid = threadIdx.x;
    const int bn = blockIdx.x << 7, bm = blockIdx.y << 7;
    const int kstart = blockIdx.z * kc, kend = kstart + kc;
    const int lane = tid & 63, wid = tid >> 6;
    const int wm = (wid & 1) << 6, wn = (wid >> 1) << 6;
    const int lrow = lane & 15, kq = lane >> 4;
    const int srow = tid >> 1;
    const int skq = (tid & 1) << 1;
    const int sk = skq << 3;

    // loop-invariant A/B source pointers
    const int gmA = bm + srow;
    const bool aval = (gmA < M);
    const u16* pAh; const u16* pAl;
    if (gmA < a1M) {
        pAh = Ah_g + (size_t)gmA * 1024;
        pAl = Al_g + (size_t)gmA * 1024;
    } else {
        int rr = aval ? (gmA - a1M) : 0;
        pAh = Rh_g + (size_t)rr * 1024;
        pAl = Rl_g + (size_t)rr * 1024;
    }
    const u16* pBh = BTh_g + (size_t)(bn + srow) * 1024;
    const u16* pBl = BTl_g + (size_t)(bn + srow) * 1024;

    f4v acc[4][4];
    #pragma unroll
    for (int i = 0; i < 4; i++)
        #pragma unroll
        for (int j = 0; j < 4; j++) acc[i][j] = 0.f;

    us8 ah0, ah1, al0, al1, bh0, bh1, bl0, bl1;
    auto loadstep = [&](int k) {
        if (aval) {
            ah0 = *(const us8*)(pAh + k + sk); ah1 = *(const us8*)(pAh + k + sk + 8);
            al0 = *(const us8*)(pAl + k + sk); al1 = *(const us8*)(pAl + k + sk + 8);
        } else { ah0 = 0; ah1 = 0; al0 = 0; al1 = 0; }
        bh0 = *(const us8*)(pBh + k + sk); bh1 = *(const us8*)(pBh + k + sk + 8);
        bl0 = *(const us8*)(pBl + k + sk); bl1 = *(const us8*)(pBl + k + sk + 8);
    };
    loadstep(kstart);

    for (int k0 = kstart; k0 < kend; k0 += 32) {
        *(us8*)&Ash[skq][srow][0] = ah0;
        *(us8*)&Ash[skq + 1][srow][0] = ah1;
        *(us8*)&Asl[skq][srow][0] = al0;
        *(us8*)&Asl[skq + 1][srow][0] = al1;
        *(us8*)&Bsh[skq][srow][0] = bh0;
        *(us8*)&Bsh[skq + 1][srow][0] = bh1;
        *(us8*)&Bsl[skq][srow][0] = bl0;
        *(us8*)&Bsl[skq + 1][srow][0] = bl1;
        __syncthreads();
        if (k0 + 32 < kend) loadstep(k0 + 32);   // prefetch overlaps MFMA below
        s8v afh[4], afl[4], bfh[4], bfl[4];
        #pragma unroll
        for (int i = 0; i < 4; i++) {
            afh[i] = *(const s8v*)&Ash[kq][wm + (i << 4) + lrow][0];
            afl[i] = *(const s8v*)&Asl[kq][wm + (i << 4) + lrow][0];
            bfh[i] = *(const s8v*)&Bsh[kq][wn + (i << 4) + lrow][0];
            bfl[i] = *(const s8v*)&Bsl[kq][wn + (i << 4) + lrow][0];
        }
        #pragma unroll
        for (int mi = 0; mi < 4; mi++)
            #pragma unroll
            for (int ni = 0; ni < 4; ni++) {
                acc[mi][ni] = __builtin_amdgcn_mfma_f32_16x16x32_bf16(
                    afh[mi], bfh[ni], acc[mi][ni], 0, 0, 0);
                acc[mi][ni] = __builtin_amdgcn_mfma_f32_16x16x32_bf16(
                    afl[mi], bfh[ni], acc[mi][ni], 0, 0, 0);
                acc[mi][ni] = __builtin_amdgcn_mfma_f32_16x16x32_bf16(
                    afh[mi], bfl[ni], acc[mi][ni], 0, 0, 0);
            }
        __syncthreads();
    }
    // epilogue: fp32 partials to C slab z. row = wm+mi*16+kq*4+i, col = wn+ni*16+lrow.
    float* Cz = C + (size_t)blockIdx.z * cS;
    #pragma unroll
    for (int mi = 0; mi < 4; mi++)
        #pragma unroll
        for (int i = 0; i < 4; i++) {
            const int gr = bm + wm + (mi << 4) + (kq << 2) + i;
            if (gr >= M) continue;
            #pragma unroll
            for (int ni = 0; ni < 4; ni++)
                Cz[(size_t)gr * 1024 + bn + wn + (ni << 4) + lrow] = acc[mi][ni][i];
        }
}

// ---- combine: sum z slabs, split hi/lo; Q rows -> Qh/Ql + fused-transpose QT;
//      D rows -> R rows (gr - a1M + a2M). 64x64 tile per block. ----
__global__ __launch_bounds__(256) void combine(
    const float* __restrict__ C, int zsplit, long cS, int a1M, int a2M, int M,
    u16* __restrict__ Qh, u16* __restrict__ Ql,
    u16* __restrict__ QTh, u16* __restrict__ QTl,
    u16* __restrict__ Rh, u16* __restrict__ Rl)
{
    __shared__ u32 T[64][65];
    const int tid = threadIdx.x;
    const int r = tid >> 2, c0 = (tid & 3) << 4;
    const int row0 = blockIdx.y << 6, col0 = blockIdx.x << 6;
    const int gr = row0 + r;
    const bool isQ = (row0 < a1M);
    alignas(16) u16 h[16], l[16];
    #pragma unroll
    for (int q = 0; q < 4; q++) {
        float4 v = make_float4(0.f, 0.f, 0.f, 0.f);
        if (gr < M) {
            const float* p = C + (size_t)gr * 1024 + col0 + c0 + q * 4;
            v = *(const float4*)p;
            for (int z = 1; z < zsplit; z++) {
                float4 t = *(const float4*)(p + (size_t)z * cS);
                v.x += t.x; v.y += t.y; v.z += t.z; v.w += t.w;
            }
        }
        float vv[4] = {v.x, v.y, v.z, v.w};
        #pragma unroll
        for (int i = 0; i < 4; i++) {
            u16 hh = f2b(vv[i]);
            u16 ll = f2b(vv[i] - b2f(hh));
            h[q * 4 + i] = hh; l[q * 4 + i] = ll;
            if (isQ) T[c0 + q * 4 + i][r] = ((u32)ll << 16) | hh;
        }
    }
    if (isQ) {
        const size_t dst = (size_t)gr * 1024 + col0 + c0;
        *(us8*)(Qh + dst) = *(const us8*)&h[0];
        *(us8*)(Qh + dst + 8) = *(const us8*)&h[8];
        *(us8*)(Ql + dst) = *(const us8*)&l[0];
        *(us8*)(Ql + dst + 8) = *(const us8*)&l[8];
        __syncthreads();
        alignas(16) u16 th[16], tl[16];
        #pragma unroll
        for (int i = 0; i < 16; i++) {
            u32 v = T[r][c0 + i];
            th[i] = (u16)(v & 0xffffu); tl[i] = (u16)(v >> 16);
        }
        const size_t dt = (size_t)(col0 + r) * 1024 + row0 + c0;
        *(us8*)(QTh + dt) = *(const us8*)&th[0];
        *(us8*)(QTh + dt + 8) = *(const us8*)&th[8];
        *(us8*)(QTl + dt) = *(const us8*)&tl[0];
        *(us8*)(QTl + dt + 8) = *(const us8*)&tl[8];
    } else if (gr < M) {
        const size_t dst = (size_t)(gr - a1M + a2M) * 1024 + col0 + c0;
        *(us8*)(Rh + dst) = *(const us8*)&h[0];
        *(us8*)(Rh + dst + 8) = *(const us8*)&h[8];
        *(us8*)(Rl + dst) = *(const us8*)&l[0];
        *(us8*)(Rl + dst + 8) = *(const us8*)&l[8];
    }
}

// ---- prefix pass1: chunk sums + weighted sums ----
__global__ __launch_bounds__(256) void prefix_pass1(
    const u16* __restrict__ Rh, const u16* __restrict__ Rl,
    float* __restrict__ csum, float* __restrict__ wpart)
{
    const int od = blockIdx.x * 256 + threadIdx.x;
    const int c = blockIdx.y;
    const u16* ph = Rh + (size_t)(c * 64) * 10240 + od;
    const u16* pl = Rl + (size_t)(c * 64) * 10240 + od;
    float cs = 0.f, wsv = 0.f;
    #pragma unroll 4
    for (int i = 0; i < 64; i++) {
        float v = b2f(ph[(size_t)i * 10240]) + b2f(pl[(size_t)i * 10240]);
        cs += v;
        wsv += (float)(511 - (c * 64 + i)) * v;
    }
    csum[c * 10240 + od] = cs;
    wpart[c * 10240 + od] = wsv;
}

// ---- prefix pass2: Acc_m fp32 ----
__global__ __launch_bounds__(256) void prefix_pass2(
    const u16* __restrict__ Rh, const u16* __restrict__ Rl,
    const float* __restrict__ csum, float* __restrict__ Acc)
{
    const int od = blockIdx.x * 256 + threadIdx.x;
    const int c = blockIdx.y;
    float run = 0.f;
    #pragma unroll
    for (int c2 = 0; c2 < 8; c2++) {
        float t = csum[c2 * 10240 + od];
        run += (c2 < c) ? t : 0.f;
    }
    const u16* ph = Rh + (size_t)(c * 64) * 10240 + od;
    const u16* pl = Rl + (size_t)(c * 64) * 10240 + od;
    float* pa = Acc + (size_t)(c * 64) * 10240 + od;
    #pragma unroll 4
    for (int i = 0; i < 64; i++) {
        run += b2f(ph[(size_t)i * 10240]) + b2f(pl[(size_t)i * 10240]);
        pa[(size_t)i * 10240] = run;
    }
}

__global__ __launch_bounds__(256) void bsum_k(
    const float* __restrict__ wpart, const float* __restrict__ Wc, float* __restrict__ bsum)
{
    const int od = blockIdx.x * 256 + threadIdx.x;
    float s = 512.f * Wc[od];
    #pragma unroll
    for (int c = 0; c < 8; c++) s += wpart[c * 10240 + od];
    bsum[od] = s;
}

// ---- contract v2: WG (j, bg): part[j][b][o] for 16 b's; wave owns 4 b's. ----
__global__ __launch_bounds__(256) void contract_k(
    const float* __restrict__ Acc, const int* __restrict__ x,
    const float* __restrict__ emb, float* __restrict__ part)
{
    __shared__ float As[10240];
    const int tid = threadIdx.x;
    const int j = blockIdx.x, bg = blockIdx.y;
    const int w = tid >> 6, lane = tid & 63;
    const int b0 = (bg << 4) + (w << 2);
    const float4* emb4 = (const float4*)emb;
    // indices + issue all e-row loads up front (latency deep)
    const int i0 = x[(b0 + 0) * 512 + j], i1 = x[(b0 + 1) * 512 + j];
    const int i2 = x[(b0 + 2) * 512 + j], i3 = x[(b0 + 3) * 512 + j];
    float4 e0[4], e1[4], e2[4], e3[4];
    #pragma unroll
    for (int c = 0; c < 4; c++) {
        e0[c] = emb4[(size_t)i0 * 256 + (c << 6) + lane];
        e1[c] = emb4[(size_t)i1 * 256 + (c << 6) + lane];
        e2[c] = emb4[(size_t)i2 * 256 + (c << 6) + lane];
        e3[c] = emb4[(size_t)i3 * 256 + (c << 6) + lane];
    }
    // stage Acc slice (40 KB)
    const float4* Ap = (const float4*)(Acc + (size_t)(511 - j) * 10240);
    float4* As4 = (float4*)As;
    #pragma unroll
    for (int i = 0; i < 10; i++) As4[tid + (i << 8)] = Ap[tid + (i << 8)];
    __syncthreads();

    float p0[10], p1[10], p2[10], p3[10];
    #pragma unroll
    for (int o = 0; o < 10; o++) {
        float s0 = 0.f, s1 = 0.f, s2 = 0.f, s3 = 0.f;
        #pragma unroll
        for (int c = 0; c < 4; c++) {
            float4 a = As4[(o << 8) + (c << 6) + lane];
            s0 = fmaf(a.x, e0[c].x, s0); s0 = fmaf(a.y, e0[c].y, s0);
            s0 = fmaf(a.z, e0[c].z, s0); s0 = fmaf(a.w, e0[c].w, s0);
            s1 = fmaf(a.x, e1[c].x, s1); s1 = fmaf(a.y, e1[c].y, s1);
            s1 = fmaf(a.z, e1[c].z, s1); s1 = fmaf(a.w, e1[c].w, s1);
            s2 = fmaf(a.x, e2[c].x, s2); s2 = fmaf(a.y, e2[c].y, s2);
            s2 = fmaf(a.z, e2[c].z, s2); s2 = fmaf(a.w, e2[c].w, s2);
            s3 = fmaf(a.x, e3[c].x, s3); s3 = fmaf(a.y, e3[c].y, s3);
            s3 = fmaf(a.z, e3[c].z, s3); s3 = fmaf(a.w, e3[c].w, s3);
        }
        p0[o] = s0; p1[o] = s1; p2[o] = s2; p3[o] = s3;
    }
    #pragma unroll
    for (int o = 0; o < 10; o++) {
        #pragma unroll
        for (int off = 32; off; off >>= 1) {
            p0[o] += __shfl_down(p0[o], off);
            p1[o] += __shfl_down(p1[o], off);
            p2[o] += __shfl_down(p2[o], off);
            p3[o] += __shfl_down(p3[o], off);
        }
    }
    if (lane == 0) {
        float* pp = part + (size_t)j * 640 + b0 * 10;
        #pragma unroll
        for (int o = 0; o < 10; o++) {
            pp[o] = p0[o]; pp[10 + o] = p1[o];
            pp[20 + o] = p2[o]; pp[30 + o] = p3[o];
        }
    }
}

__global__ __launch_bounds__(256) void reduce_part(
    const float* __restrict__ part, float* __restrict__ pred)
{
    const int gid = blockIdx.x * 256 + threadIdx.x;
    const int out = gid >> 4, s = gid & 15;
    float p = 0.f;
    #pragma unroll 8
    for (int t = 0; t < 32; t++) p += part[(size_t)(s + (t << 4)) * 640 + out];
    for (int off = 8; off; off >>= 1) p += __shfl_down(p, off, 16);
    if (s == 0) pred[out] = p;
}

__global__ __launch_bounds__(640) void finalize_k(
    const float* __restrict__ pred, const float* __restrict__ bsum,
    const float* __restrict__ bvec, const float* __restrict__ bc,
    const int* __restrict__ label, float* __restrict__ out)
{
    __shared__ float biasv[10];
    const int tid = threadIdx.x;
    {
        int o = tid >> 6, lane = tid & 63;
        float s = 0.f;
        for (int k = lane; k < 1024; k += 64) s = fmaf(bsum[o * 1024 + k], bvec[k], s);
        for (int off = 32; off; off >>= 1) s += __shfl_down(s, off, 64);
        if (lane == 0) biasv[o] = s;
    }
    __syncthreads();
    if (tid < 64) {
        int b = tid, lab = label[b];
        float v[10], mx = -1e30f;
        #pragma unroll
        for (int o = 0; o < 10; o++) {
            v[o] = (pred[b * 10 + o] + biasv[o]) * (1.f / 512.f) + bc[o];
            mx = fmaxf(mx, v[o]);
        }
        float se = 0.f, vl = 0.f;
        #pragma unroll
        for (int o = 0; o < 10; o++) {
            se += __expf(v[o] - mx);
            if (o == lab) vl = v[o];
        }
        float myloss = (mx + __logf(se)) - vl;
        for (int off = 32; off; off >>= 1) myloss += __shfl_down(myloss, off, 64);
        if (tid == 0) out[0] = myloss * (1.f / 64.f);
    }
}

extern "C" void kernel_launch(void* const* d_in, const int* in_sizes, int n_in,
                              void* d_out, int out_size, void* d_ws, size_t ws_size,
                              hipStream_t stream) {
    const int*   x     = (const int*)d_in[0];
    const int*   label = (const int*)d_in[1];
    const float* emb   = (const float*)d_in[2];
    const float* W     = (const float*)d_in[3];
    const float* bvec  = (const float*)d_in[4];
    const float* Wc    = (const float*)d_in[5];
    const float* bc    = (const float*)d_in[6];
    float* ws    = (float*)d_ws;
    float* C     = ws + OFF_C;
    float* Acc   = ws + OFF_C;          // overlay: used after last combine
    float* csum  = ws + OFF_CS;
    float* wpart = ws + OFF_WP;
    float* bsum  = ws + OFF_BS;
    float* pred  = ws + OFF_PRED;
    float* part  = ws + OFF_PART;
    u16*   ub    = (u16*)(ws + OFF_U16);
    u16* RH = ub + URH;
    u16* RL = ub + URL;
    u16* qin[4]  = {ub + UQAH, ub + UQAL, ub + UQATH, ub + UQATL};
    u16* qout[4] = {ub + UQBH, ub + UQBL, ub + UQBTH, ub + UQBTL};
    float* out   = (float*)d_out;

    split_w<<<dim3(16, 16), 256, 0, stream>>>(W, qin[0], qin[1], qin[2], qin[3]);
    thin_d0<<<dim3(40, 8), 256, 0, stream>>>(Wc, W, C);
    d0_fin<<<40, 256, 0, stream>>>(C, RH, RL);

    int a2M = 10;
    for (int k = 2; k <= 10; k++) {
        const int a1M = (k < 10) ? 1024 : 0;
        const int M = a1M + a2M;
        const int zs = (M <= 1376) ? 4 : 2;
        const long cS = (zs == 4) ? CS4 : CS2;
        const int kc = 1024 / zs;
        dim3 g(8, (M + 127) / 128, zs);
        gemm_mfma<<<g, 256, 0, stream>>>(qin[0], qin[1], RH, RL, qin[2], qin[3],
                                         C, a1M, a2M, kc, cS);
        combine<<<dim3(16, (M + 63) / 64), 256, 0, stream>>>(
            C, zs, cS, a1M, a2M, M,
            qout[0], qout[1], qout[2], qout[3], RH, RL);
        for (int i = 0; i < 4; i++) { u16* t = qin[i]; qin[i] = qout[i]; qout[i] = t; }
        a2M <<= 1;
    }

    prefix_pass1<<<dim3(40, 8), 256, 0, stream>>>(RH, RL, csum, wpart);
    prefix_pass2<<<dim3(40, 8), 256, 0, stream>>>(RH, RL, csum, Acc);
    bsum_k<<<40, 256, 0, stream>>>(wpart, Wc, bsum);
    contract_k<<<dim3(512, 4), 256, 0, stream>>>(Acc, x, emb, part);
    reduce_part<<<40, 256, 0, stream>>>(part, pred);
    finalize_k<<<1, 640, 0, stream>>>(pred, bsum, bvec, bc, label, out);
}